// Round 14
// baseline (206.158 us; speedup 1.0000x reference)
//
#include <hip/hip_runtime.h>

// ---------------- problem constants ----------------
#define DM    1024      // D_MODEL
#define DS    16        // D_STATE
#define DI    2048      // D_INNER
#define LSEQ  2048      // SEQ
#define BL    4096      // BATCH * SEQ rows
#define NC    64        // scan chunks
#define CHK   32        // LSEQ / NC

typedef float          f32x4  __attribute__((ext_vector_type(4)));
typedef unsigned int   u32x4  __attribute__((ext_vector_type(4)));
typedef unsigned short u16x8  __attribute__((ext_vector_type(8)));

#if __has_builtin(__builtin_amdgcn_exp2f)
#define EXP2(x) __builtin_amdgcn_exp2f(x)      // raw v_exp_f32
#else
#define EXP2(x) __expf((x) * 0.6931471805599453f)
#endif

#if __has_builtin(__builtin_amdgcn_rcpf)
#define RCP(x) __builtin_amdgcn_rcpf(x)        // raw v_rcp_f32
#else
#define RCP(x) (1.f / (x))
#endif

#if __has_builtin(__builtin_elementwise_fma)
#define VFMA(a, b, c) __builtin_elementwise_fma((a), (b), (c))
#else
__device__ __forceinline__ f32x4 VFMA(f32x4 a, f32x4 b, f32x4 c) {
    f32x4 r;
    r[0] = fmaf(a[0], b[0], c[0]); r[1] = fmaf(a[1], b[1], c[1]);
    r[2] = fmaf(a[2], b[2], c[2]); r[3] = fmaf(a[3], b[3], c[3]);
    return r;
}
#endif

__device__ __forceinline__ unsigned short f2bf(float f) {
    unsigned int u = __float_as_uint(f);
    u += 0x7fffu + ((u >> 16) & 1u);      // round-to-nearest-even
    return (unsigned short)(u >> 16);
}

__device__ __forceinline__ float bf2f(unsigned short u) {
    return __uint_as_float((unsigned int)u << 16);
}

__device__ __forceinline__ float silu_f(float x) {
    return x * RCP(1.f + EXP2(-1.44269504f * x));
}

__device__ __forceinline__ void mfma_bf16(f32x4& d, const u32x4& a, const u32x4& b) {
    asm("v_mfma_f32_16x16x32_bf16 %0, %1, %2, %0" : "+v"(d) : "v"(a), "v"(b));
}

__device__ __forceinline__ void gload16(const void* g, void* l) {
    __builtin_amdgcn_global_load_lds(
        (const __attribute__((address_space(1))) unsigned int*)g,
        (__attribute__((address_space(3))) unsigned int*)l, 16, 0, 0);
}

// ---------------- fused input converts: x -> xbf, W_in -> wbf ----------------
__global__ __launch_bounds__(256) void prep_inputs_kernel(const float* __restrict__ x,
                                                          const float* __restrict__ W_in,
                                                          unsigned short* __restrict__ xbf,
                                                          unsigned short* __restrict__ wbf) {
    const int n4 = (BL * DM) / 4;                 // 1,048,576 float4 each
    int i = blockIdx.x * 256 + threadIdx.x;       // 0 .. 2*n4-1
    const float* src = (i < n4) ? x : W_in;
    unsigned short* dst = (i < n4) ? xbf : wbf;
    int j = (i < n4) ? i : i - n4;
    float4 v = *(const float4*)(src + j * 4);
    ushort4 o;
    o.x = f2bf(v.x); o.y = f2bf(v.y); o.z = f2bf(v.z); o.w = f2bf(v.w);
    *(ushort4*)(dst + j * 4) = o;
}

// ---- fused weight prep: W_out -> wobf, W_x -> padded wxbf, A_log -> A2 ------
__global__ __launch_bounds__(256) void prep_weights_kernel(const float* __restrict__ W_out,
                                                           const float* __restrict__ Wx,
                                                           const float* __restrict__ A_log,
                                                           unsigned short* __restrict__ wobf,
                                                           unsigned short* __restrict__ wxbf,
                                                           float* __restrict__ A2) {
    const int n4 = (DM * DI) / 4;                 // 524,288 float4
    int i = blockIdx.x * 256 + threadIdx.x;       // grid 3200*256 = 819,200
    if (i < n4) {
        float4 v = *(const float4*)(W_out + i * 4);
        ushort4 o;
        o.x = f2bf(v.x); o.y = f2bf(v.y); o.z = f2bf(v.z); o.w = f2bf(v.w);
        *(ushort4*)(wobf + i * 4) = o;
    } else {
        int j = i - n4;                            // 0 .. 262,143 : W_x pad
        if (j < 128 * 2048) {
            int e = j >> 11;
            wxbf[j] = (e < 33) ? f2bf(Wx[j]) : (unsigned short)0;
        } else {
            int k = j - 128 * 2048;                // 0 .. 32,767 : A2 table
            if (k < DI * DS) A2[k] = -__expf(A_log[k]) * 1.44269504f;
        }
    }
}

// ---------------- 256x256 MFMA GEMM, 4-deep pipeline, counted vmcnt ----------
template <typename OUT>
__global__ __launch_bounds__(512, 2) void gemm256_bf16_nt(const unsigned short* __restrict__ A,
                                                          const unsigned short* __restrict__ B,
                                                          OUT* __restrict__ C,
                                                          int M, int N, int K) {
    __shared__ unsigned short As[4][256 * 32];    // 64 KB
    __shared__ unsigned short Bs[4][256 * 32];    // 64 KB

    const int tid  = threadIdx.x;
    const int lane = tid & 63;
    const int wave = tid >> 6;          // 0..7
    const int wm = wave >> 2;           // 0..1  (M half)
    const int wn = wave & 3;            // 0..3  (N quarter)
    const int lrow = lane & 15, lkh = lane >> 4;
    const int swa  = (lrow >> 1) & 3;   // read-side swizzle

    const long m0 = (long)blockIdx.y * 256;
    const long n0 = (long)blockIdx.x * 256;

    const int scb = ((tid & 3) ^ ((tid >> 3) & 3)) * 8;
    const unsigned short* pa = A + (m0 + (tid >> 2)) * K + scb;
    const unsigned short* pb = B + (n0 + (tid >> 2)) * K + scb;
    const long rstep = (long)128 * K;

    const int NT = K >> 5;

    f32x4 acc[8][4];
#pragma unroll
    for (int i = 0; i < 8; ++i)
#pragma unroll
        for (int j = 0; j < 4; ++j)
            acc[i][j] = (f32x4){0.f, 0.f, 0.f, 0.f};

#define STAGE_A(t) { char* d_ = (char*)&As[(t) & 3][0] + wave * 1024;          \
                     gload16(pa + (long)(t) * 32,         d_);                 \
                     gload16(pa + rstep + (long)(t) * 32, d_ + 8192); }
#define STAGE_B(t) { char* d_ = (char*)&Bs[(t) & 3][0] + wave * 1024;          \
                     gload16(pb + (long)(t) * 32,         d_);                 \
                     gload16(pb + rstep + (long)(t) * 32, d_ + 8192); }

    STAGE_A(0); STAGE_B(0);
    STAGE_A(1); STAGE_B(1);
    STAGE_A(2); STAGE_B(2);
    asm volatile("s_waitcnt vmcnt(8)" ::: "memory");
    __builtin_amdgcn_s_barrier();
    __builtin_amdgcn_sched_barrier(0);

    for (int t = 0; t < NT; ++t) {
        const unsigned short* as = &As[t & 3][0];
        const unsigned short* bs = &Bs[t & 3][0];
        const bool st = (t + 3 < NT);

        u32x4 af[4], bfr[4];
#pragma unroll
        for (int j = 0; j < 4; ++j)
            bfr[j] = *(const u32x4*)(bs + (wn * 64 + j * 16 + lrow) * 32 + ((lkh ^ swa) * 8));
#pragma unroll
        for (int i = 0; i < 4; ++i)
            af[i] = *(const u32x4*)(as + (wm * 128 + i * 16 + lrow) * 32 + ((lkh ^ swa) * 8));
        if (st) STAGE_A(t + 3);
        asm volatile("s_waitcnt lgkmcnt(0)" ::: "memory");
        __builtin_amdgcn_sched_barrier(0);
        __builtin_amdgcn_s_setprio(1);
#pragma unroll
        for (int i = 0; i < 4; ++i)
#pragma unroll
            for (int j = 0; j < 4; ++j)
                mfma_bf16(acc[i][j], af[i], bfr[j]);
        __builtin_amdgcn_s_setprio(0);

#pragma unroll
        for (int i = 0; i < 4; ++i)
            af[i] = *(const u32x4*)(as + (wm * 128 + (i + 4) * 16 + lrow) * 32 + ((lkh ^ swa) * 8));
        if (st) STAGE_B(t + 3);
        asm volatile("s_waitcnt lgkmcnt(0)" ::: "memory");
        __builtin_amdgcn_sched_barrier(0);
        __builtin_amdgcn_s_setprio(1);
#pragma unroll
        for (int i = 0; i < 4; ++i)
#pragma unroll
            for (int j = 0; j < 4; ++j)
                mfma_bf16(acc[i + 4][j], af[i], bfr[j]);
        __builtin_amdgcn_s_setprio(0);

        if (t < NT - 1) {
            if (t <= NT - 4)      asm volatile("s_waitcnt vmcnt(8)" ::: "memory");
            else if (t == NT - 3) asm volatile("s_waitcnt vmcnt(4)" ::: "memory");
            else                  asm volatile("s_waitcnt vmcnt(0)" ::: "memory");
            __builtin_amdgcn_s_barrier();
            __builtin_amdgcn_sched_barrier(0);
        }
    }
#undef STAGE_A
#undef STAGE_B

    asm volatile("s_nop 7\n\ts_nop 7" ::: "memory");

#pragma unroll
    for (int i = 0; i < 8; ++i)
#pragma unroll
        for (int j = 0; j < 4; ++j)
#pragma unroll
            for (int r = 0; r < 4; ++r) {
                long row = m0 + wm * 128 + i * 16 + lkh * 4 + r;
                long col = n0 + wn * 64 + j * 16 + lrow;
                float v = acc[i][j][r];
                if constexpr (sizeof(OUT) == 2) C[row * (long)N + col] = f2bf(v);
                else                            C[row * (long)N + col] = v;
            }
}

// ------- 128x(NF*32) MFMA GEMM, 4-deep pipeline, counted vmcnt (gemm2/3) -----
template <int NF, typename OUT>
__global__ __launch_bounds__(256) void gemm_bf16_nt(const unsigned short* __restrict__ A,
                                                    const unsigned short* __restrict__ B,
                                                    OUT* __restrict__ C,
                                                    int M, int N, int K, int KS) {
    constexpr int BN = NF * 32;
    __shared__ unsigned short As[4][128 * 32];    // 64 KB
    __shared__ unsigned short Bs[4][BN * 32];     // 16/32 KB

    const int tid  = threadIdx.x;
    const int lane = tid & 63;
    const int wave = tid >> 6;
    const int wr = wave >> 1, wc = wave & 1;
    const int lrow = lane & 15, lkh = lane >> 4;

    const long m0 = (long)blockIdx.y * 128;
    const long n0 = (long)blockIdx.x * BN;
    const int koff = blockIdx.z * KS;

    const int scb = ((tid & 3) ^ ((tid >> 3) & 3)) * 8;
    const unsigned short* pa = A + (m0 + (tid >> 2)) * K + koff + scb;
    const unsigned short* pb = B + (n0 + (tid >> 2)) * K + koff + scb;
    const long half = (long)64 * K;

    OUT* Cz = C + (long)blockIdx.z * M * (long)N;

    const int swa = (lrow >> 1) & 3;
    const int NT = KS >> 5;

    f32x4 acc[4][NF];
#pragma unroll
    for (int i = 0; i < 4; ++i)
#pragma unroll
        for (int j = 0; j < NF; ++j)
            acc[i][j] = (f32x4){0.f, 0.f, 0.f, 0.f};

#define STAGE128(t) {                                                          \
        char* a_ = (char*)&As[(t) & 3][0] + wave * 1024;                       \
        gload16(pa + (long)(t) * 32,        a_);                               \
        gload16(pa + half + (long)(t) * 32, a_ + 4096);                        \
        char* b_ = (char*)&Bs[(t) & 3][0] + wave * 1024;                       \
        gload16(pb + (long)(t) * 32, b_);                                      \
        if constexpr (NF == 4) gload16(pb + half + (long)(t) * 32, b_ + 4096); }

    STAGE128(0); STAGE128(1); STAGE128(2);
    if constexpr (NF == 4) asm volatile("s_waitcnt vmcnt(8)" ::: "memory");
    else                   asm volatile("s_waitcnt vmcnt(6)" ::: "memory");
    __builtin_amdgcn_s_barrier();
    __builtin_amdgcn_sched_barrier(0);

    for (int t = 0; t < NT; ++t) {
        const unsigned short* as = &As[t & 3][0];
        const unsigned short* bs = &Bs[t & 3][0];

        u32x4 af[4], bfr[NF];
#pragma unroll
        for (int i = 0; i < 4; ++i)
            af[i] = *(const u32x4*)(as + (wr * 64 + i * 16 + lrow) * 32 + ((lkh ^ swa) * 8));
#pragma unroll
        for (int j = 0; j < NF; ++j)
            bfr[j] = *(const u32x4*)(bs + (wc * NF * 16 + j * 16 + lrow) * 32 + ((lkh ^ swa) * 8));
        if (t + 3 < NT) STAGE128(t + 3);
        asm volatile("s_waitcnt lgkmcnt(0)" ::: "memory");
        __builtin_amdgcn_sched_barrier(0);
        __builtin_amdgcn_s_setprio(1);
#pragma unroll
        for (int i = 0; i < 4; ++i)
#pragma unroll
            for (int j = 0; j < NF; ++j)
                mfma_bf16(acc[i][j], af[i], bfr[j]);
        __builtin_amdgcn_s_setprio(0);

        if (t < NT - 1) {
            if (t <= NT - 4) {
                if constexpr (NF == 4) asm volatile("s_waitcnt vmcnt(8)" ::: "memory");
                else                   asm volatile("s_waitcnt vmcnt(6)" ::: "memory");
            } else if (t == NT - 3) {
                if constexpr (NF == 4) asm volatile("s_waitcnt vmcnt(4)" ::: "memory");
                else                   asm volatile("s_waitcnt vmcnt(3)" ::: "memory");
            } else {
                asm volatile("s_waitcnt vmcnt(0)" ::: "memory");
            }
            __builtin_amdgcn_s_barrier();
            __builtin_amdgcn_sched_barrier(0);
        }
    }
#undef STAGE128

    asm volatile("s_nop 7\n\ts_nop 7" ::: "memory");

#pragma unroll
    for (int i = 0; i < 4; ++i)
#pragma unroll
        for (int j = 0; j < NF; ++j)
#pragma unroll
            for (int r = 0; r < 4; ++r) {
                long row = m0 + wr * 64 + i * 16 + lkh * 4 + r;
                long col = n0 + wc * NF * 16 + j * 16 + lrow;
                float v = acc[i][j][r];
                if constexpr (sizeof(OUT) == 2) Cz[row * (long)N + col] = f2bf(v);
                else                            Cz[row * (long)N + col] = v;
            }
}

// ---------------- depthwise causal conv(4) + bias + SiLU -> bf16 ----------------
__global__ __launch_bounds__(256) void conv_silu_kernel(const unsigned short* __restrict__ xzbf,
                                                        const float* __restrict__ cw,
                                                        const float* __restrict__ cb,
                                                        unsigned short* __restrict__ xcbf) {
    int idx = blockIdx.x * 256 + threadIdx.x;     // BL * DI / 8
    int d8 = (idx & 255) * 8;
    int m  = idx >> 8;
    int t  = m & (LSEQ - 1);
    const unsigned short* p = xzbf + (long)m * (2 * DI) + d8;
    u16x8 tap0 = (u16x8)(0), tap1 = (u16x8)(0), tap2 = (u16x8)(0);
    u16x8 tap3 = *(const u16x8*)(p);
    if (t >= 1) tap2 = *(const u16x8*)(p - 1 * 2 * DI);
    if (t >= 2) tap1 = *(const u16x8*)(p - 2 * 2 * DI);
    if (t >= 3) tap0 = *(const u16x8*)(p - 3 * 2 * DI);

    u16x8 o;
#pragma unroll
    for (int k = 0; k < 8; ++k) {
        const float4 wv = *(const float4*)(cw + 4 * (d8 + k));
        float s = cb[d8 + k];
        s = fmaf(bf2f(tap0[k]), wv.x, s);
        s = fmaf(bf2f(tap1[k]), wv.y, s);
        s = fmaf(bf2f(tap2[k]), wv.z, s);
        s = fmaf(bf2f(tap3[k]), wv.w, s);
        o[k] = f2bf(silu_f(s));
    }
    *(u16x8*)(xcbf + (long)m * DI + d8) = o;
}

// sum 8 K-split partials of xdbl[4096][128]; softplus(col0)=dlt, cols 1..32 -> BC
__global__ __launch_bounds__(256) void xdbl_reduce_kernel(const float* __restrict__ part,
                                                          float* __restrict__ dlt,
                                                          float* __restrict__ BC) {
    int idx = blockIdx.x * 256 + threadIdx.x;     // BL * 33
    if (idx >= BL * 33) return;
    int m = idx / 33;
    int j = idx - m * 33;
    float v = 0.f;
#pragma unroll
    for (int g = 0; g < 8; ++g) v += part[(long)g * (BL * 128) + (long)m * 128 + j];
    if (j == 0) dlt[m] = (v > 20.f) ? v : log1pf(expf(v));
    else        BC[(long)m * 32 + (j - 1)] = v;
}

// ---------------- selective scan, chunked-parallel (NC=64, CHK=32) -----------
// R13 packed-math inner + LDS bulk-staging of streaming operands (u, z):
// whole chunk panel loaded coalesced (16B/lane) before the loop -> per-step
// reads are ds_read_u16 (2-way bank aliasing = free), zero VGPR cost.
// delta/B/C stay wave-uniform global (scalar loads, L1-resident).
__global__ __launch_bounds__(256) void scan_pass1(const float* __restrict__ dlt,
                                                  const float* __restrict__ BC,
                                                  const unsigned short* __restrict__ xcbf,
                                                  const float* __restrict__ A2t,
                                                  float* __restrict__ P_,
                                                  float* __restrict__ S_) {
    __shared__ unsigned short su[CHK * 256];   // 16 KB

    const int tid = threadIdx.x;
    const int c   = blockIdx.x;
    const int ch  = blockIdx.y * 256 + tid;
    const int b   = ch >> 11;
    const int d   = ch & (DI - 1);
    const int d0  = (blockIdx.y * 256) & (DI - 1);
    const long m0 = (long)b * LSEQ + (long)c * CHK;

    // stage u panel: 32 rows x 256 ch, coalesced u16x8 per thread x4
#pragma unroll
    for (int r = 0; r < 4; ++r) {
        int idx = r * 256 + tid;               // 0..1023
        int t   = idx >> 5;                    // 0..31
        int c8  = (idx & 31) * 8;              // 0..248
        *(u16x8*)(su + t * 256 + c8) = *(const u16x8*)(xcbf + (m0 + t) * DI + d0 + c8);
    }

    const float* ap = A2t + d * 16;
    const f32x4 A2a = *(const f32x4*)(ap + 0);
    const f32x4 A2b = *(const f32x4*)(ap + 4);
    const f32x4 A2c = *(const f32x4*)(ap + 8);
    const f32x4 A2d = *(const f32x4*)(ap + 12);
    f32x4 ha = (f32x4){0.f, 0.f, 0.f, 0.f};
    f32x4 hb = ha, hc = ha, hd = ha;

    const float* br = BC + m0 * 32;     // wave-uniform
    const float* dr = dlt + m0;         // wave-uniform
    float sumdl = 0.f;
    __syncthreads();

#pragma unroll 4
    for (int t = 0; t < CHK; ++t) {
        float dl = dr[t];
        float du = dl * bf2f(su[t * 256 + tid]);
        sumdl += dl;
        f32x4 duv = (f32x4){du, du, du, du};
        f32x4 ea, eb, ec, ed;
#pragma unroll
        for (int j = 0; j < 4; ++j) {
            ea[j] = EXP2(dl * A2a[j]);
            eb[j] = EXP2(dl * A2b[j]);
            ec[j] = EXP2(dl * A2c[j]);
            ed[j] = EXP2(dl * A2d[j]);
        }
        ha = VFMA(ea, ha, duv * (*(const f32x4*)(br + t * 32 + 0)));
        hb = VFMA(eb, hb, duv * (*(const f32x4*)(br + t * 32 + 4)));
        hc = VFMA(ec, hc, duv * (*(const f32x4*)(br + t * 32 + 8)));
        hd = VFMA(ed, hd, duv * (*(const f32x4*)(br + t * 32 + 12)));
    }
    float* pp = P_ + ((long)c * 4096 + ch) * 16;
    float* sp = S_ + ((long)c * 4096 + ch) * 16;
    f32x4 pv;
#pragma unroll
    for (int j = 0; j < 4; ++j) pv[j] = EXP2(A2a[j] * sumdl);
    *(f32x4*)(pp + 0) = pv;
#pragma unroll
    for (int j = 0; j < 4; ++j) pv[j] = EXP2(A2b[j] * sumdl);
    *(f32x4*)(pp + 4) = pv;
#pragma unroll
    for (int j = 0; j < 4; ++j) pv[j] = EXP2(A2c[j] * sumdl);
    *(f32x4*)(pp + 8) = pv;
#pragma unroll
    for (int j = 0; j < 4; ++j) pv[j] = EXP2(A2d[j] * sumdl);
    *(f32x4*)(pp + 12) = pv;
    *(f32x4*)(sp + 0)  = ha;
    *(f32x4*)(sp + 4)  = hb;
    *(f32x4*)(sp + 8)  = hc;
    *(f32x4*)(sp + 12) = hd;
}

__global__ __launch_bounds__(256) void scan_pass2(const float* __restrict__ P_,
                                                  float* __restrict__ S_) {
    const long idx = (long)blockIdx.x * 256 + threadIdx.x;  // (ch*16+s), 0..65535
    float h = 0.f;
    for (int c0 = 0; c0 < NC; c0 += 8) {
        float p[8], s[8];
#pragma unroll
        for (int i = 0; i < 8; ++i) {
            p[i] = P_[(long)(c0 + i) * 65536 + idx];
            s[i] = S_[(long)(c0 + i) * 65536 + idx];
        }
#pragma unroll
        for (int i = 0; i < 8; ++i) {
            S_[(long)(c0 + i) * 65536 + idx] = h;   // h0 entering chunk c0+i
            h = fmaf(p[i], h, s[i]);
        }
    }
}

__global__ __launch_bounds__(256) void scan_pass3(const float* __restrict__ dlt,
                                                  const float* __restrict__ BC,
                                                  const unsigned short* __restrict__ xcbf,
                                                  const unsigned short* __restrict__ xzbf,
                                                  const float* __restrict__ A2t,
                                                  const float* __restrict__ H0,
                                                  unsigned short* __restrict__ ybf) {
    __shared__ unsigned short su[CHK * 256];   // 16 KB
    __shared__ unsigned short sz[CHK * 256];   // 16 KB

    const int tid = threadIdx.x;
    const int c   = blockIdx.x;
    const int ch  = blockIdx.y * 256 + tid;
    const int b   = ch >> 11;
    const int d   = ch & (DI - 1);
    const int d0  = (blockIdx.y * 256) & (DI - 1);
    const long m0 = (long)b * LSEQ + (long)c * CHK;

    // stage u and z panels (coalesced)
#pragma unroll
    for (int r = 0; r < 4; ++r) {
        int idx = r * 256 + tid;
        int t   = idx >> 5;
        int c8  = (idx & 31) * 8;
        *(u16x8*)(su + t * 256 + c8) = *(const u16x8*)(xcbf + (m0 + t) * DI + d0 + c8);
        *(u16x8*)(sz + t * 256 + c8) = *(const u16x8*)(xzbf + (m0 + t) * (2 * DI) + DI + d0 + c8);
    }

    const float* ap = A2t + d * 16;
    const f32x4 A2a = *(const f32x4*)(ap + 0);
    const f32x4 A2b = *(const f32x4*)(ap + 4);
    const f32x4 A2c = *(const f32x4*)(ap + 8);
    const f32x4 A2d = *(const f32x4*)(ap + 12);
    const float* h0p = H0 + ((long)c * 4096 + ch) * 16;
    f32x4 ha = *(const f32x4*)(h0p + 0);
    f32x4 hb = *(const f32x4*)(h0p + 4);
    f32x4 hc = *(const f32x4*)(h0p + 8);
    f32x4 hd = *(const f32x4*)(h0p + 12);

    const float* br = BC + m0 * 32;     // wave-uniform
    const float* dr = dlt + m0;         // wave-uniform
    unsigned short* yr = ybf + m0 * DI + d;
    __syncthreads();

#pragma unroll 4
    for (int t = 0; t < CHK; ++t) {
        float dl = dr[t];
        float du = dl * bf2f(su[t * 256 + tid]);
        float z  = bf2f(sz[t * 256 + tid]);
        f32x4 duv = (f32x4){du, du, du, du};
        f32x4 ea, eb, ec, ed;
#pragma unroll
        for (int j = 0; j < 4; ++j) {
            ea[j] = EXP2(dl * A2a[j]);
            eb[j] = EXP2(dl * A2b[j]);
            ec[j] = EXP2(dl * A2c[j]);
            ed[j] = EXP2(dl * A2d[j]);
        }
        ha = VFMA(ea, ha, duv * (*(const f32x4*)(br + t * 32 + 0)));
        hb = VFMA(eb, hb, duv * (*(const f32x4*)(br + t * 32 + 4)));
        hc = VFMA(ec, hc, duv * (*(const f32x4*)(br + t * 32 + 8)));
        hd = VFMA(ed, hd, duv * (*(const f32x4*)(br + t * 32 + 12)));
        f32x4 yv = ha * (*(const f32x4*)(br + t * 32 + 16));
        yv = VFMA(hb, *(const f32x4*)(br + t * 32 + 20), yv);
        yv = VFMA(hc, *(const f32x4*)(br + t * 32 + 24), yv);
        yv = VFMA(hd, *(const f32x4*)(br + t * 32 + 28), yv);
        float y = (yv[0] + yv[1]) + (yv[2] + yv[3]);
        yr[(long)t * DI] = f2bf(y * silu_f(z));
    }
}

// ---------------- host launcher ----------------
extern "C" void kernel_launch(void* const* d_in, const int* in_sizes, int n_in,
                              void* d_out, int out_size, void* d_ws, size_t ws_size,
                              hipStream_t stream) {
    const float* x      = (const float*)d_in[0];   // [2,2048,1024]
    const float* W_in   = (const float*)d_in[1];   // [4096,1024]
    const float* conv_w = (const float*)d_in[2];   // [2048,1,4]
    const float* conv_b = (const float*)d_in[3];   // [2048]
    const float* A_log  = (const float*)d_in[4];   // [2048,16]
    const float* W_x    = (const float*)d_in[5];   // [33,2048]
    const float* W_out  = (const float*)d_in[6];   // [1024,2048]
    float* out = (float*)d_out;                    // [2,2048,1024]

    char* w = (char*)d_ws;
    unsigned short* xbf  = (unsigned short*)(w + 0);          //  8,388,608 B
    unsigned short* wbf  = (unsigned short*)(w + 8388608);    //  8,388,608 B
    unsigned short* xzbf = (unsigned short*)(w + 16777216);   // 33,554,432 B  [4096][4096] bf16
    unsigned short* xcbf = (unsigned short*)(w + 50331648);   // 16,777,216 B
    float*          dlt  = (float*)(w + 67108864);            //     16,384 B
    float*          BC   = (float*)(w + 67125248);            //    524,288 B
    float*          P_   = (float*)(w + 67649536);            // 16,777,216 B  [64][4096][16]
    float*          S_   = (float*)(w + 84426752);            // 16,777,216 B
    float*          A2   = (float*)(w + 101203968);           //    131,072 B  (end 101,335,040)

    // regions reused (stream-ordered):
    unsigned short* wobf      = xbf;                          // W_out bf16 (4.2 MB, over xbf after gemm1)
    unsigned short* wxbf      = (unsigned short*)(w + 8388608);   // [128][2048] bf16 (0.5 MB, over wbf)
    float*          xdbl_part = (float*)P_;                   // [8][4096][128] f32 (16.8 MB, over P_ pre-scan)
    unsigned short* ybf       = (unsigned short*)P_;          // y*silu(z) bf16 (over P_ after pass2)

    // 1) fused input converts (x, W_in)
    prep_inputs_kernel<<<dim3(8192), dim3(256), 0, stream>>>(x, W_in, xbf, wbf);
    // 2) xz = x @ W_in^T   (M=4096, N=4096, K=1024) -> bf16, 256^2 4-deep pipeline
    gemm256_bf16_nt<unsigned short><<<dim3(16, 16), dim3(512), 0, stream>>>(xbf, wbf, xzbf, BL, 2 * DI, DM);
    // 3) fused weight prep (W_out, W_x pad, A2 table)
    prep_weights_kernel<<<dim3(3200), dim3(256), 0, stream>>>(W_out, W_x, A_log, wobf, wxbf, A2);
    // 4) depthwise conv + SiLU -> bf16
    conv_silu_kernel<<<dim3((BL * DI / 8) / 256), dim3(256), 0, stream>>>(xzbf, conv_w, conv_b, xcbf);
    // 5) xdbl = xc @ W_x^T via MFMA, K-split x8 -> partials, then reduce+softplus/split
    gemm_bf16_nt<4, float><<<dim3(1, 32, 8), dim3(256), 0, stream>>>(xcbf, wxbf, xdbl_part, BL, 128, DI, 256);
    xdbl_reduce_kernel<<<dim3(528), dim3(256), 0, stream>>>(xdbl_part, dlt, BC);
    // 6) chunked selective scan (NC=64, CHK=32) — LDS-staged u/z
    scan_pass1<<<dim3(NC, 16), dim3(256), 0, stream>>>(dlt, BC, xcbf, A2, P_, S_);
    scan_pass2<<<dim3(256), dim3(256), 0, stream>>>(P_, S_);
    scan_pass3<<<dim3(NC, 16), dim3(256), 0, stream>>>(dlt, BC, xcbf, xzbf, A2, S_, ybf);
    // 7) out = y @ W_out^T   (M=4096, N=1024, K=2048) -> fp32, 128x64 tiles, 4-deep pipeline
    gemm_bf16_nt<2, float><<<dim3(16, 32, 1), dim3(256), 0, stream>>>(ybf, wobf, out, BL, DM, DI, DI);
}

// Round 15
// 195.858 us; speedup vs baseline: 1.0526x; 1.0526x over previous
//
#include <hip/hip_runtime.h>

// ---------------- problem constants ----------------
#define DM    1024      // D_MODEL
#define DS    16        // D_STATE
#define DI    2048      // D_INNER
#define LSEQ  2048      // SEQ
#define BL    4096      // BATCH * SEQ rows
#define NC    64        // scan chunks
#define CHK   32        // LSEQ / NC

typedef float          f32x4  __attribute__((ext_vector_type(4)));
typedef float          f32x16 __attribute__((ext_vector_type(16)));
typedef unsigned int   u32x4  __attribute__((ext_vector_type(4)));
typedef unsigned short u16x8  __attribute__((ext_vector_type(8)));

#if __has_builtin(__builtin_amdgcn_exp2f)
#define EXP2(x) __builtin_amdgcn_exp2f(x)      // raw v_exp_f32
#else
#define EXP2(x) __expf((x) * 0.6931471805599453f)
#endif

#if __has_builtin(__builtin_amdgcn_rcpf)
#define RCP(x) __builtin_amdgcn_rcpf(x)        // raw v_rcp_f32
#else
#define RCP(x) (1.f / (x))
#endif

__device__ __forceinline__ unsigned short f2bf(float f) {
    unsigned int u = __float_as_uint(f);
    u += 0x7fffu + ((u >> 16) & 1u);      // round-to-nearest-even
    return (unsigned short)(u >> 16);
}

__device__ __forceinline__ float bf2f(unsigned short u) {
    return __uint_as_float((unsigned int)u << 16);
}

__device__ __forceinline__ float silu_f(float x) {
    return x * RCP(1.f + EXP2(-1.44269504f * x));
}

__device__ __forceinline__ void mfma_bf16(f32x4& d, const u32x4& a, const u32x4& b) {
    asm("v_mfma_f32_16x16x32_bf16 %0, %1, %2, %0" : "+v"(d) : "v"(a), "v"(b));
}

__device__ __forceinline__ void gload16(const void* g, void* l) {
    __builtin_amdgcn_global_load_lds(
        (const __attribute__((address_space(1))) unsigned int*)g,
        (__attribute__((address_space(3))) unsigned int*)l, 16, 0, 0);
}

// ---------------- fused prep: x,W_in -> bf16; W_out -> bf16; W_x pad; A2 -----
// runs BEFORE gemm1 (wobf/wxbf have dedicated workspace regions).
__global__ __launch_bounds__(256) void prep_all_kernel(const float* __restrict__ x,
                                                       const float* __restrict__ W_in,
                                                       const float* __restrict__ W_out,
                                                       const float* __restrict__ Wx,
                                                       const float* __restrict__ A_log,
                                                       unsigned short* __restrict__ xbf,
                                                       unsigned short* __restrict__ wbf,
                                                       unsigned short* __restrict__ wobf,
                                                       unsigned short* __restrict__ wxbf,
                                                       float* __restrict__ A2) {
    const int n4  = (BL * DM) / 4;                // 1,048,576 float4 (x), same for W_in
    const int nW4 = (DM * DI) / 4;                // 524,288 float4 (W_out)
    int i = blockIdx.x * 256 + threadIdx.x;       // grid 11392*256 = 2,916,352

    if (i < 2 * n4) {
        const float* src = (i < n4) ? x : W_in;
        unsigned short* dst = (i < n4) ? xbf : wbf;
        int j = (i < n4) ? i : i - n4;
        float4 v = *(const float4*)(src + j * 4);
        ushort4 o;
        o.x = f2bf(v.x); o.y = f2bf(v.y); o.z = f2bf(v.z); o.w = f2bf(v.w);
        *(ushort4*)(dst + j * 4) = o;
        return;
    }
    i -= 2 * n4;                                   // 0 .. 819,199
    if (i < nW4) {
        float4 v = *(const float4*)(W_out + i * 4);
        ushort4 o;
        o.x = f2bf(v.x); o.y = f2bf(v.y); o.z = f2bf(v.z); o.w = f2bf(v.w);
        *(ushort4*)(wobf + i * 4) = o;
    } else {
        int j = i - nW4;                           // 0 .. 294,911
        if (j < 128 * 2048) {                      // W_x zero-pad to [128][2048]
            int e = j >> 11;
            wxbf[j] = (e < 33) ? f2bf(Wx[j]) : (unsigned short)0;
        } else {
            int k = j - 128 * 2048;                // A2 table (32,768)
            if (k < DI * DS) A2[k] = -__expf(A_log[k]) * 1.44269504f;
        }
    }
}

// ---------------- 256x256 MFMA GEMM, 4-deep pipeline, counted vmcnt ----------
template <typename OUT>
__global__ __launch_bounds__(512, 2) void gemm256_bf16_nt(const unsigned short* __restrict__ A,
                                                          const unsigned short* __restrict__ B,
                                                          OUT* __restrict__ C,
                                                          int M, int N, int K) {
    __shared__ unsigned short As[4][256 * 32];    // 64 KB
    __shared__ unsigned short Bs[4][256 * 32];    // 64 KB

    const int tid  = threadIdx.x;
    const int lane = tid & 63;
    const int wave = tid >> 6;          // 0..7
    const int wm = wave >> 2;           // 0..1  (M half)
    const int wn = wave & 3;            // 0..3  (N quarter)
    const int lrow = lane & 15, lkh = lane >> 4;
    const int swa  = (lrow >> 1) & 3;   // read-side swizzle

    const long m0 = (long)blockIdx.y * 256;
    const long n0 = (long)blockIdx.x * 256;

    const int scb = ((tid & 3) ^ ((tid >> 3) & 3)) * 8;
    const unsigned short* pa = A + (m0 + (tid >> 2)) * K + scb;
    const unsigned short* pb = B + (n0 + (tid >> 2)) * K + scb;
    const long rstep = (long)128 * K;

    const int NT = K >> 5;

    f32x4 acc[8][4];
#pragma unroll
    for (int i = 0; i < 8; ++i)
#pragma unroll
        for (int j = 0; j < 4; ++j)
            acc[i][j] = (f32x4){0.f, 0.f, 0.f, 0.f};

#define STAGE_A(t) { char* d_ = (char*)&As[(t) & 3][0] + wave * 1024;          \
                     gload16(pa + (long)(t) * 32,         d_);                 \
                     gload16(pa + rstep + (long)(t) * 32, d_ + 8192); }
#define STAGE_B(t) { char* d_ = (char*)&Bs[(t) & 3][0] + wave * 1024;          \
                     gload16(pb + (long)(t) * 32,         d_);                 \
                     gload16(pb + rstep + (long)(t) * 32, d_ + 8192); }

    STAGE_A(0); STAGE_B(0);
    STAGE_A(1); STAGE_B(1);
    STAGE_A(2); STAGE_B(2);
    asm volatile("s_waitcnt vmcnt(8)" ::: "memory");
    __builtin_amdgcn_s_barrier();
    __builtin_amdgcn_sched_barrier(0);

    for (int t = 0; t < NT; ++t) {
        const unsigned short* as = &As[t & 3][0];
        const unsigned short* bs = &Bs[t & 3][0];
        const bool st = (t + 3 < NT);

        u32x4 af[4], bfr[4];
#pragma unroll
        for (int j = 0; j < 4; ++j)
            bfr[j] = *(const u32x4*)(bs + (wn * 64 + j * 16 + lrow) * 32 + ((lkh ^ swa) * 8));
#pragma unroll
        for (int i = 0; i < 4; ++i)
            af[i] = *(const u32x4*)(as + (wm * 128 + i * 16 + lrow) * 32 + ((lkh ^ swa) * 8));
        if (st) STAGE_A(t + 3);
        asm volatile("s_waitcnt lgkmcnt(0)" ::: "memory");
        __builtin_amdgcn_sched_barrier(0);
        __builtin_amdgcn_s_setprio(1);
#pragma unroll
        for (int i = 0; i < 4; ++i)
#pragma unroll
            for (int j = 0; j < 4; ++j)
                mfma_bf16(acc[i][j], af[i], bfr[j]);
        __builtin_amdgcn_s_setprio(0);

#pragma unroll
        for (int i = 0; i < 4; ++i)
            af[i] = *(const u32x4*)(as + (wm * 128 + (i + 4) * 16 + lrow) * 32 + ((lkh ^ swa) * 8));
        if (st) STAGE_B(t + 3);
        asm volatile("s_waitcnt lgkmcnt(0)" ::: "memory");
        __builtin_amdgcn_sched_barrier(0);
        __builtin_amdgcn_s_setprio(1);
#pragma unroll
        for (int i = 0; i < 4; ++i)
#pragma unroll
            for (int j = 0; j < 4; ++j)
                mfma_bf16(acc[i + 4][j], af[i], bfr[j]);
        __builtin_amdgcn_s_setprio(0);

        if (t < NT - 1) {
            if (t <= NT - 4)      asm volatile("s_waitcnt vmcnt(8)" ::: "memory");
            else if (t == NT - 3) asm volatile("s_waitcnt vmcnt(4)" ::: "memory");
            else                  asm volatile("s_waitcnt vmcnt(0)" ::: "memory");
            __builtin_amdgcn_s_barrier();
            __builtin_amdgcn_sched_barrier(0);
        }
    }
#undef STAGE_A
#undef STAGE_B

    asm volatile("s_nop 7\n\ts_nop 7" ::: "memory");

#pragma unroll
    for (int i = 0; i < 8; ++i)
#pragma unroll
        for (int j = 0; j < 4; ++j)
#pragma unroll
            for (int r = 0; r < 4; ++r) {
                long row = m0 + wm * 128 + i * 16 + lkh * 4 + r;
                long col = n0 + wn * 64 + j * 16 + lrow;
                float v = acc[i][j][r];
                if constexpr (sizeof(OUT) == 2) C[row * (long)N + col] = f2bf(v);
                else                            C[row * (long)N + col] = v;
            }
}

// ------- 128x(NF*32) MFMA GEMM, 4-deep pipeline, counted vmcnt (gemm2/3) -----
template <int NF, typename OUT>
__global__ __launch_bounds__(256) void gemm_bf16_nt(const unsigned short* __restrict__ A,
                                                    const unsigned short* __restrict__ B,
                                                    OUT* __restrict__ C,
                                                    int M, int N, int K, int KS) {
    constexpr int BN = NF * 32;
    __shared__ unsigned short As[4][128 * 32];    // 64 KB
    __shared__ unsigned short Bs[4][BN * 32];     // 16/32 KB

    const int tid  = threadIdx.x;
    const int lane = tid & 63;
    const int wave = tid >> 6;
    const int wr = wave >> 1, wc = wave & 1;
    const int lrow = lane & 15, lkh = lane >> 4;

    const long m0 = (long)blockIdx.y * 128;
    const long n0 = (long)blockIdx.x * BN;
    const int koff = blockIdx.z * KS;

    const int scb = ((tid & 3) ^ ((tid >> 3) & 3)) * 8;
    const unsigned short* pa = A + (m0 + (tid >> 2)) * K + koff + scb;
    const unsigned short* pb = B + (n0 + (tid >> 2)) * K + koff + scb;
    const long half = (long)64 * K;

    OUT* Cz = C + (long)blockIdx.z * M * (long)N;

    const int swa = (lrow >> 1) & 3;
    const int NT = KS >> 5;

    f32x4 acc[4][NF];
#pragma unroll
    for (int i = 0; i < 4; ++i)
#pragma unroll
        for (int j = 0; j < NF; ++j)
            acc[i][j] = (f32x4){0.f, 0.f, 0.f, 0.f};

#define STAGE128(t) {                                                          \
        char* a_ = (char*)&As[(t) & 3][0] + wave * 1024;                       \
        gload16(pa + (long)(t) * 32,        a_);                               \
        gload16(pa + half + (long)(t) * 32, a_ + 4096);                        \
        char* b_ = (char*)&Bs[(t) & 3][0] + wave * 1024;                       \
        gload16(pb + (long)(t) * 32, b_);                                      \
        if constexpr (NF == 4) gload16(pb + half + (long)(t) * 32, b_ + 4096); }

    STAGE128(0); STAGE128(1); STAGE128(2);
    if constexpr (NF == 4) asm volatile("s_waitcnt vmcnt(8)" ::: "memory");
    else                   asm volatile("s_waitcnt vmcnt(6)" ::: "memory");
    __builtin_amdgcn_s_barrier();
    __builtin_amdgcn_sched_barrier(0);

    for (int t = 0; t < NT; ++t) {
        const unsigned short* as = &As[t & 3][0];
        const unsigned short* bs = &Bs[t & 3][0];

        u32x4 af[4], bfr[NF];
#pragma unroll
        for (int i = 0; i < 4; ++i)
            af[i] = *(const u32x4*)(as + (wr * 64 + i * 16 + lrow) * 32 + ((lkh ^ swa) * 8));
#pragma unroll
        for (int j = 0; j < NF; ++j)
            bfr[j] = *(const u32x4*)(bs + (wc * NF * 16 + j * 16 + lrow) * 32 + ((lkh ^ swa) * 8));
        if (t + 3 < NT) STAGE128(t + 3);
        asm volatile("s_waitcnt lgkmcnt(0)" ::: "memory");
        __builtin_amdgcn_sched_barrier(0);
        __builtin_amdgcn_s_setprio(1);
#pragma unroll
        for (int i = 0; i < 4; ++i)
#pragma unroll
            for (int j = 0; j < NF; ++j)
                mfma_bf16(acc[i][j], af[i], bfr[j]);
        __builtin_amdgcn_s_setprio(0);

        if (t < NT - 1) {
            if (t <= NT - 4) {
                if constexpr (NF == 4) asm volatile("s_waitcnt vmcnt(8)" ::: "memory");
                else                   asm volatile("s_waitcnt vmcnt(6)" ::: "memory");
            } else if (t == NT - 3) {
                if constexpr (NF == 4) asm volatile("s_waitcnt vmcnt(4)" ::: "memory");
                else                   asm volatile("s_waitcnt vmcnt(3)" ::: "memory");
            } else {
                asm volatile("s_waitcnt vmcnt(0)" ::: "memory");
            }
            __builtin_amdgcn_s_barrier();
            __builtin_amdgcn_sched_barrier(0);
        }
    }
#undef STAGE128

    asm volatile("s_nop 7\n\ts_nop 7" ::: "memory");

#pragma unroll
    for (int i = 0; i < 4; ++i)
#pragma unroll
        for (int j = 0; j < NF; ++j)
#pragma unroll
            for (int r = 0; r < 4; ++r) {
                long row = m0 + wr * 64 + i * 16 + lkh * 4 + r;
                long col = n0 + wc * NF * 16 + j * 16 + lrow;
                float v = acc[i][j][r];
                if constexpr (sizeof(OUT) == 2) Cz[row * (long)N + col] = f2bf(v);
                else                            Cz[row * (long)N + col] = v;
            }
}

// ---------------- depthwise causal conv(4) + bias + SiLU -> bf16 ----------------
__global__ __launch_bounds__(256) void conv_silu_kernel(const unsigned short* __restrict__ xzbf,
                                                        const float* __restrict__ cw,
                                                        const float* __restrict__ cb,
                                                        unsigned short* __restrict__ xcbf) {
    int idx = blockIdx.x * 256 + threadIdx.x;     // BL * DI / 8
    int d8 = (idx & 255) * 8;
    int m  = idx >> 8;
    int t  = m & (LSEQ - 1);
    const unsigned short* p = xzbf + (long)m * (2 * DI) + d8;
    u16x8 tap0 = (u16x8)(0), tap1 = (u16x8)(0), tap2 = (u16x8)(0);
    u16x8 tap3 = *(const u16x8*)(p);
    if (t >= 1) tap2 = *(const u16x8*)(p - 1 * 2 * DI);
    if (t >= 2) tap1 = *(const u16x8*)(p - 2 * 2 * DI);
    if (t >= 3) tap0 = *(const u16x8*)(p - 3 * 2 * DI);

    u16x8 o;
#pragma unroll
    for (int k = 0; k < 8; ++k) {
        const float4 wv = *(const float4*)(cw + 4 * (d8 + k));
        float s = cb[d8 + k];
        s = fmaf(bf2f(tap0[k]), wv.x, s);
        s = fmaf(bf2f(tap1[k]), wv.y, s);
        s = fmaf(bf2f(tap2[k]), wv.z, s);
        s = fmaf(bf2f(tap3[k]), wv.w, s);
        o[k] = f2bf(silu_f(s));
    }
    *(u16x8*)(xcbf + (long)m * DI + d8) = o;
}

// sum 8 K-split partials of xdbl[4096][128]; softplus(col0)=dlt, cols 1..32 -> BC
__global__ __launch_bounds__(256) void xdbl_reduce_kernel(const float* __restrict__ part,
                                                          float* __restrict__ dlt,
                                                          float* __restrict__ BC) {
    int idx = blockIdx.x * 256 + threadIdx.x;     // BL * 33
    if (idx >= BL * 33) return;
    int m = idx / 33;
    int j = idx - m * 33;
    float v = 0.f;
#pragma unroll
    for (int g = 0; g < 8; ++g) v += part[(long)g * (BL * 128) + (long)m * 128 + j];
    if (j == 0) dlt[m] = (v > 20.f) ? v : log1pf(expf(v));
    else        BC[(long)m * 32 + (j - 1)] = v;
}

// ---------------- selective scan, chunked-parallel (NC=64, CHK=32) -----------
// R11 form (best measured, 200.4 us): delta/B/C via wave-uniform global loads
// (L1-resident); t unrolled x4 with batched u/z prefetch; 4 partial y chains;
// raw v_exp_f32; A2 precomputed.
__global__ __launch_bounds__(256) void scan_pass1(const float* __restrict__ dlt,
                                                  const float* __restrict__ BC,
                                                  const unsigned short* __restrict__ xcbf,
                                                  const float* __restrict__ A2t,
                                                  float* __restrict__ P_,
                                                  float* __restrict__ S_) {
    const int tid = threadIdx.x;
    const int c   = blockIdx.x;
    const int ch  = blockIdx.y * 256 + tid;
    const int b   = ch >> 11;
    const int d   = ch & (DI - 1);
    const long m0 = (long)b * LSEQ + (long)c * CHK;

    f32x16 A2, h;
    {
        const float* ap = A2t + d * 16;
        f32x4 a0 = *(const f32x4*)(ap + 0);
        f32x4 a1 = *(const f32x4*)(ap + 4);
        f32x4 a2 = *(const f32x4*)(ap + 8);
        f32x4 a3 = *(const f32x4*)(ap + 12);
#pragma unroll
        for (int j = 0; j < 4; ++j) {
            A2[j] = a0[j]; A2[4 + j] = a1[j]; A2[8 + j] = a2[j]; A2[12 + j] = a3[j];
            h[j] = 0.f; h[4 + j] = 0.f; h[8 + j] = 0.f; h[12 + j] = 0.f;
        }
    }
    const unsigned short* ur = xcbf + m0 * DI + d;
    const float* br = BC + m0 * 32;     // wave-uniform
    const float* dr = dlt + m0;         // wave-uniform
    float sumdl = 0.f;

#pragma unroll
    for (int t0 = 0; t0 < CHK; t0 += 4) {
        float uu[4];
#pragma unroll
        for (int k = 0; k < 4; ++k) uu[k] = bf2f(ur[(long)(t0 + k) * DI]);
#pragma unroll
        for (int k = 0; k < 4; ++k) {
            const int t = t0 + k;
            float dl = dr[t];
            float du = dl * uu[k];
            sumdl += dl;
#pragma unroll
            for (int q = 0; q < 4; ++q) {
                f32x4 bq = *(const f32x4*)(br + t * 32 + q * 4);
#pragma unroll
                for (int j = 0; j < 4; ++j) {
                    const int s = q * 4 + j;
                    float dA = EXP2(dl * A2[s]);
                    h[s] = fmaf(dA, h[s], du * bq[j]);
                }
            }
        }
    }
    float* pp = P_ + ((long)c * 4096 + ch) * 16;
    float* sp = S_ + ((long)c * 4096 + ch) * 16;
#pragma unroll
    for (int q = 0; q < 4; ++q) {
        f32x4 pv;
#pragma unroll
        for (int j = 0; j < 4; ++j) pv[j] = EXP2(A2[q * 4 + j] * sumdl);
        *(f32x4*)(pp + q * 4) = pv;
        *(f32x4*)(sp + q * 4) = (f32x4){h[q*4], h[q*4+1], h[q*4+2], h[q*4+3]};
    }
}

__global__ __launch_bounds__(256) void scan_pass2(const float* __restrict__ P_,
                                                  float* __restrict__ S_) {
    const long idx = (long)blockIdx.x * 256 + threadIdx.x;  // (ch*16+s), 0..65535
    float h = 0.f;
    for (int c0 = 0; c0 < NC; c0 += 8) {
        float p[8], s[8];
#pragma unroll
        for (int i = 0; i < 8; ++i) {
            p[i] = P_[(long)(c0 + i) * 65536 + idx];
            s[i] = S_[(long)(c0 + i) * 65536 + idx];
        }
#pragma unroll
        for (int i = 0; i < 8; ++i) {
            S_[(long)(c0 + i) * 65536 + idx] = h;   // h0 entering chunk c0+i
            h = fmaf(p[i], h, s[i]);
        }
    }
}

__global__ __launch_bounds__(256) void scan_pass3(const float* __restrict__ dlt,
                                                  const float* __restrict__ BC,
                                                  const unsigned short* __restrict__ xcbf,
                                                  const unsigned short* __restrict__ xzbf,
                                                  const float* __restrict__ A2t,
                                                  const float* __restrict__ H0,
                                                  unsigned short* __restrict__ ybf) {
    const int tid = threadIdx.x;
    const int c   = blockIdx.x;
    const int ch  = blockIdx.y * 256 + tid;
    const int b   = ch >> 11;
    const int d   = ch & (DI - 1);
    const long m0 = (long)b * LSEQ + (long)c * CHK;

    f32x16 A2, h;
    {
        const float* ap = A2t + d * 16;
        f32x4 a0 = *(const f32x4*)(ap + 0);
        f32x4 a1 = *(const f32x4*)(ap + 4);
        f32x4 a2 = *(const f32x4*)(ap + 8);
        f32x4 a3 = *(const f32x4*)(ap + 12);
        const float* h0p = H0 + ((long)c * 4096 + ch) * 16;
        f32x4 h0a = *(const f32x4*)(h0p + 0);
        f32x4 h0b = *(const f32x4*)(h0p + 4);
        f32x4 h0c = *(const f32x4*)(h0p + 8);
        f32x4 h0d = *(const f32x4*)(h0p + 12);
#pragma unroll
        for (int j = 0; j < 4; ++j) {
            A2[j] = a0[j]; A2[4 + j] = a1[j]; A2[8 + j] = a2[j]; A2[12 + j] = a3[j];
            h[j] = h0a[j]; h[4 + j] = h0b[j]; h[8 + j] = h0c[j]; h[12 + j] = h0d[j];
        }
    }

    const unsigned short* ur = xcbf + m0 * DI + d;
    const unsigned short* zr = xzbf + m0 * (2 * DI) + DI + d;
    const float* br = BC + m0 * 32;     // wave-uniform
    const float* dr = dlt + m0;         // wave-uniform
    unsigned short* yr = ybf + m0 * DI + d;

#pragma unroll
    for (int t0 = 0; t0 < CHK; t0 += 4) {
        float uu[4], zz[4];
#pragma unroll
        for (int k = 0; k < 4; ++k) {
            uu[k] = bf2f(ur[(long)(t0 + k) * DI]);
            zz[k] = bf2f(zr[(long)(t0 + k) * 2 * DI]);
        }
#pragma unroll
        for (int k = 0; k < 4; ++k) {
            const int t = t0 + k;
            float dl = dr[t];
            float du = dl * uu[k];
            f32x4 yv = (f32x4){0.f, 0.f, 0.f, 0.f};   // 4 partial y chains
#pragma unroll
            for (int q = 0; q < 4; ++q) {
                f32x4 bq = *(const f32x4*)(br + t * 32 + q * 4);
                f32x4 cq = *(const f32x4*)(br + t * 32 + 16 + q * 4);
#pragma unroll
                for (int j = 0; j < 4; ++j) {
                    const int s = q * 4 + j;
                    float dA = EXP2(dl * A2[s]);
                    h[s] = fmaf(dA, h[s], du * bq[j]);
                    yv[q] = fmaf(h[s], cq[j], yv[q]);
                }
            }
            float y = (yv[0] + yv[1]) + (yv[2] + yv[3]);
            yr[(long)t * DI] = f2bf(y * silu_f(zz[k]));
        }
    }
}

// ---------------- host launcher ----------------
extern "C" void kernel_launch(void* const* d_in, const int* in_sizes, int n_in,
                              void* d_out, int out_size, void* d_ws, size_t ws_size,
                              hipStream_t stream) {
    const float* x      = (const float*)d_in[0];   // [2,2048,1024]
    const float* W_in   = (const float*)d_in[1];   // [4096,1024]
    const float* conv_w = (const float*)d_in[2];   // [2048,1,4]
    const float* conv_b = (const float*)d_in[3];   // [2048]
    const float* A_log  = (const float*)d_in[4];   // [2048,16]
    const float* W_x    = (const float*)d_in[5];   // [33,2048]
    const float* W_out  = (const float*)d_in[6];   // [1024,2048]
    float* out = (float*)d_out;                    // [2,2048,1024]

    char* w = (char*)d_ws;
    unsigned short* xbf  = (unsigned short*)(w + 0);          //  8,388,608 B
    unsigned short* wbf  = (unsigned short*)(w + 8388608);    //  8,388,608 B
    unsigned short* xzbf = (unsigned short*)(w + 16777216);   // 33,554,432 B  [4096][4096] bf16
    unsigned short* xcbf = (unsigned short*)(w + 50331648);   // 16,777,216 B
    float*          dlt  = (float*)(w + 67108864);            //     16,384 B
    float*          BC   = (float*)(w + 67125248);            //    524,288 B
    float*          P_   = (float*)(w + 67649536);            // 16,777,216 B  [64][4096][16]
    float*          S_   = (float*)(w + 84426752);            // 16,777,216 B
    float*          A2   = (float*)(w + 101203968);           //    131,072 B
    unsigned short* wobf = (unsigned short*)(w + 101335040);  //  4,194,304 B  (own region)
    unsigned short* wxbf = (unsigned short*)(w + 105529344);  //    524,288 B  (end 106,053,632)

    // regions reused (stream-ordered):
    float*          xdbl_part = (float*)P_;                   // [8][4096][128] f32 (over P_ pre-scan)
    unsigned short* ybf       = (unsigned short*)P_;          // y*silu(z) bf16 (over P_ after pass2)

    // 1) all input/weight prep in one launch (wobf/wxbf no longer alias xbf/wbf)
    prep_all_kernel<<<dim3(11392), dim3(256), 0, stream>>>(x, W_in, W_out, W_x, A_log,
                                                           xbf, wbf, wobf, wxbf, A2);
    // 2) xz = x @ W_in^T   (M=4096, N=4096, K=1024) -> bf16, 256^2 4-deep pipeline
    gemm256_bf16_nt<unsigned short><<<dim3(16, 16), dim3(512), 0, stream>>>(xbf, wbf, xzbf, BL, 2 * DI, DM);
    // 3) depthwise conv + SiLU -> bf16
    conv_silu_kernel<<<dim3((BL * DI / 8) / 256), dim3(256), 0, stream>>>(xzbf, conv_w, conv_b, xcbf);
    // 4) xdbl = xc @ W_x^T via MFMA, K-split x8 -> partials, then reduce+softplus/split
    gemm_bf16_nt<4, float><<<dim3(1, 32, 8), dim3(256), 0, stream>>>(xcbf, wxbf, xdbl_part, BL, 128, DI, 256);
    xdbl_reduce_kernel<<<dim3(528), dim3(256), 0, stream>>>(xdbl_part, dlt, BC);
    // 5) chunked selective scan (NC=64, CHK=32) — R11 form
    scan_pass1<<<dim3(NC, 16), dim3(256), 0, stream>>>(dlt, BC, xcbf, A2, P_, S_);
    scan_pass2<<<dim3(256), dim3(256), 0, stream>>>(P_, S_);
    scan_pass3<<<dim3(NC, 16), dim3(256), 0, stream>>>(dlt, BC, xcbf, xzbf, A2, S_, ybf);
    // 6) out = y @ W_out^T   (M=4096, N=1024, K=2048) -> fp32, 128x64 tiles, 4-deep pipeline
    gemm_bf16_nt<2, float><<<dim3(16, 32, 1), dim3(256), 0, stream>>>(ybf, wobf, out, BL, DM, DI, DI);
}